// Round 2
// baseline (1467.078 us; speedup 1.0000x reference)
//
#include <hip/hip_runtime.h>

// Linear-RNN chunked parallel scan, fp16 MFMA (fp32 accum).
//   h_{t+1} = [x_t | h_t | c_t] @ Wh^T   (row-vector form: h' = h@M + u_t)
//   o_t     = [x_t | h_t | c_t] @ Wo^T
// Phase1: per (batch, 32-step block) chains from 0 (block0 from hidden) -> v_i
// Phase2: Hillis-Steele scan over 64 blocks with M^(32*2^r) powers (fp16 squarings)
// Phase3: rerun blocks from true start states, emit o_t and h_final.
// fp16 (not bf16): 4x lower quant noise at identical MFMA rate; values are O(1)
// (h stationary sigma~1, W sigma~0.043) so fp16 range is safe; accum is fp32.
// Workspace: WfT (0.56MB) + 11 M-power pairs (11MB) + V0/V1 (33.5MB) ~= 46MB.

typedef __attribute__((ext_vector_type(8))) _Float16 half8;
typedef __attribute__((ext_vector_type(4))) float f32x4;

#define B_ 256
#define T_ 2048
#define NB 64
#define KS 32
#define ISTRIDE 552   // inter row stride in elements (16B-aligned rows, 2-way-max LDS banks)

__device__ __forceinline__ unsigned short f2h(float f) {
  union { _Float16 h; unsigned short u; } v;
  v.h = (_Float16)f;
  return v.u;
}
__device__ __forceinline__ float h2f(unsigned u16) {
  union { unsigned short u; _Float16 h; } v;
  v.u = (unsigned short)u16;
  return (float)v.h;
}

// Build WfT: [17 chunks][512 n][32 k'] fp16, inter k-order = [h(512)|x(16)|c(1)|pad(15)]
// Mplain: [512 k][512 j] fp16 with M[k][j] = Wh[j][16+k]; M0t32 = T32 layout of M (= first 16 chunks of WfT).
__global__ void prep_kernel(const float* __restrict__ Wh,
                            unsigned short* __restrict__ WfT,
                            unsigned short* __restrict__ Mplain,
                            unsigned short* __restrict__ M0t32) {
  int idx = blockIdx.x * blockDim.x + threadIdx.x;
  if (idx < 17 * 16384) {
    int kc = idx >> 14, r = idx & 16383, n = r >> 5, kk = r & 31;
    int k = kc * 32 + kk;
    float v = 0.f;
    if (k < 512) v = Wh[n * 529 + 16 + k];
    else if (k < 528) v = Wh[n * 529 + (k - 512)];
    else if (k == 528) v = Wh[n * 529 + 528];
    unsigned short b = f2h(v);
    WfT[idx] = b;
    if (k < 512) M0t32[idx] = b;
  } else {
    int i2 = idx - 17 * 16384;
    if (i2 < 262144) {
      int k = i2 >> 9, j = i2 & 511;
      Mplain[i2] = f2h(Wh[j * 529 + 16 + k]);
    }
  }
}

// 64-row x 512-col x K=512 MFMA block: A plain fp16 (lda=512) from global, B in T32 layout.
__device__ __forceinline__ void gemm64_core(const unsigned short* __restrict__ A,
                                            const unsigned short* __restrict__ Bt,
                                            f32x4 (&acc)[4][4]) {
  const int tid = threadIdx.x;
  const int wid = tid >> 6, lane = tid & 63, q = lane >> 4, l15 = lane & 15;
  const int c0 = wid * 64;
  #pragma unroll
  for (int rt = 0; rt < 4; ++rt)
    #pragma unroll
    for (int ct = 0; ct < 4; ++ct) { f32x4 z = {0.f, 0.f, 0.f, 0.f}; acc[rt][ct] = z; }
  for (int kc = 0; kc < 16; ++kc) {
    half8 a[4], b[4];
    #pragma unroll
    for (int rt = 0; rt < 4; ++rt)
      a[rt] = *(const half8*)(A + (rt * 16 + l15) * 512 + kc * 32 + q * 8);
    #pragma unroll
    for (int ct = 0; ct < 4; ++ct)
      b[ct] = *(const half8*)(Bt + kc * 16384 + (c0 + ct * 16 + l15) * 32 + q * 8);
    #pragma unroll
    for (int rt = 0; rt < 4; ++rt)
      #pragma unroll
      for (int ct = 0; ct < 4; ++ct)
        acc[rt][ct] = __builtin_amdgcn_mfma_f32_16x16x32_f16(a[rt], b[ct], acc[rt][ct], 0, 0, 0);
  }
}

// C = A @ B, write plain + T32 (for next squaring / scan use). grid 8, 512 thr.
__global__ __launch_bounds__(512, 2) void sq_kernel(const unsigned short* __restrict__ A,
                                                    const unsigned short* __restrict__ Bt,
                                                    unsigned short* __restrict__ outP,
                                                    unsigned short* __restrict__ outT) {
  const int row0 = blockIdx.x * 64;
  f32x4 acc[4][4];
  gemm64_core(A + row0 * 512, Bt, acc);
  const int tid = threadIdx.x;
  const int wid = tid >> 6, lane = tid & 63, q = lane >> 4, l15 = lane & 15;
  const int c0 = wid * 64;
  #pragma unroll
  for (int rt = 0; rt < 4; ++rt)
    for (int ct = 0; ct < 4; ++ct)
      for (int r = 0; r < 4; ++r) {
        int row = row0 + rt * 16 + q * 4 + r;
        int col = c0 + ct * 16 + l15;
        unsigned short v = f2h(acc[rt][ct][r]);
        outP[row * 512 + col] = v;
        outT[(row >> 5) * 16384 + col * 32 + (row & 31)] = v;
      }
}

// Hillis-Steele round: Vdst[i] = (i>=d ? Vsrc[i-d]@Bt : 0) + Vsrc[i]. grid 256 (i x 4 bgroups).
__global__ __launch_bounds__(512, 2) void scan_kernel(const unsigned short* __restrict__ Vsrc,
                                                      unsigned short* __restrict__ Vdst,
                                                      const unsigned short* __restrict__ Bt,
                                                      int d) {
  const int bx = blockIdx.x;
  const int i = bx >> 2, bg = bx & 3;
  const int vr0 = i * 256 + bg * 64;
  const int tid = threadIdx.x;
  if (i >= d) {
    f32x4 acc[4][4];
    gemm64_core(Vsrc + (size_t)(vr0 - d * 256) * 512, Bt, acc);
    const int wid = tid >> 6, lane = tid & 63, q = lane >> 4, l15 = lane & 15;
    const int c0 = wid * 64;
    #pragma unroll
    for (int rt = 0; rt < 4; ++rt)
      for (int ct = 0; ct < 4; ++ct)
        for (int r = 0; r < 4; ++r) {
          int row = vr0 + rt * 16 + q * 4 + r;
          int col = c0 + ct * 16 + l15;
          float v = acc[rt][ct][r] + h2f(Vsrc[(size_t)row * 512 + col]);
          Vdst[(size_t)row * 512 + col] = f2h(v);
        }
  } else {
    for (int it = tid; it < 4096; it += 512) {
      int row = it >> 6, n8 = (it & 63) * 8;
      *(uint4*)(Vdst + (size_t)(vr0 + row) * 512 + n8) =
          *(const uint4*)(Vsrc + (size_t)(vr0 + row) * 512 + n8);
    }
  }
}

// Chunk kernel: PHASE=1 -> v_i to Vdst; PHASE=3 -> o_t + h_final, starts from Vsrc/hidden.
// grid 256 = (block i)*4 + bgroup(64 rows). 512 threads = 8 waves, wave = 64 rows x 64 cols.
template <int PHASE>
__global__ __launch_bounds__(512, 2) void chunk_kernel(
    const float* __restrict__ x, const float* __restrict__ hidden,
    const float* __restrict__ cost, const float* __restrict__ Wo,
    const unsigned short* __restrict__ WfT,
    const unsigned short* __restrict__ Vsrc,
    unsigned short* __restrict__ Vdst,
    float* __restrict__ out) {
  __shared__ unsigned short inter[64 * ISTRIDE];
  __shared__ float wo_lds[544];
  const int tid = threadIdx.x;
  const int bx = blockIdx.x;
  const int i_blk = bx >> 2, bg = bx & 3, b0 = bg * 64;
  const int wid = tid >> 6, lane = tid & 63, q = lane >> 4, l15 = lane & 15;
  const int c0 = wid * 64;
  const int row8 = tid >> 3, s8 = tid & 7;

  for (int idx = tid; idx < 64 * ISTRIDE; idx += 512) inter[idx] = 0;
  if (PHASE == 3) {
    for (int k = tid; k < 544; k += 512) {
      float v = 0.f;
      if (k < 512) v = Wo[16 + k];
      else if (k < 528) v = Wo[k - 512];
      else if (k == 528) v = Wo[528];
      wo_lds[k] = v;
    }
  }
  __syncthreads();
  // initial state into inter h-part
  if (i_blk == 0) {
    for (int nn = 0; nn < 64; nn += 4) {
      int n = s8 * 64 + nn;
      float4 hv = *(const float4*)(hidden + (size_t)(b0 + row8) * 512 + n);
      unsigned short* ip = &inter[row8 * ISTRIDE + n];
      ip[0] = f2h(hv.x); ip[1] = f2h(hv.y); ip[2] = f2h(hv.z); ip[3] = f2h(hv.w);
    }
  } else if (PHASE == 3) {
    const unsigned short* vp = Vsrc + ((size_t)(i_blk - 1) * 256 + b0 + row8) * 512;
    for (int nn = 0; nn < 64; nn += 8) {
      int n = s8 * 64 + nn;
      *(uint4*)&inter[row8 * ISTRIDE + n] = *(const uint4*)(vp + n);
    }
  }
  // stage x/c for j=0
  {
    int t0 = i_blk * KS;
    const float* xp = x + ((size_t)(b0 + row8) * T_ + t0) * 16 + s8 * 2;
    float2 xv = *(const float2*)xp;
    unsigned u = (unsigned)f2h(xv.x) | ((unsigned)f2h(xv.y) << 16);
    *(unsigned*)&inter[row8 * ISTRIDE + 512 + s8 * 2] = u;
    if (tid < 64) inter[tid * ISTRIDE + 528] = f2h(cost[(size_t)(b0 + tid) * T_ + t0]);
  }

  f32x4 acc[4][4];
  for (int j = 0; j < KS; ++j) {
    __syncthreads();  // inter (h_j, x_j, c_j) ready
    const int t = i_blk * KS + j;
    #pragma unroll
    for (int rt = 0; rt < 4; ++rt)
      #pragma unroll
      for (int ct = 0; ct < 4; ++ct) { f32x4 z = {0.f, 0.f, 0.f, 0.f}; acc[rt][ct] = z; }
    for (int kc = 0; kc < 17; ++kc) {
      half8 a[4], b[4];
      #pragma unroll
      for (int rt = 0; rt < 4; ++rt)
        a[rt] = *(const half8*)&inter[(rt * 16 + l15) * ISTRIDE + kc * 32 + q * 8];
      #pragma unroll
      for (int ct = 0; ct < 4; ++ct)
        b[ct] = *(const half8*)(WfT + kc * 16384 + (c0 + ct * 16 + l15) * 32 + q * 8);
      #pragma unroll
      for (int rt = 0; rt < 4; ++rt)
        #pragma unroll
        for (int ct = 0; ct < 4; ++ct)
          acc[rt][ct] = __builtin_amdgcn_mfma_f32_16x16x32_f16(a[rt], b[ct], acc[rt][ct], 0, 0, 0);
    }
    if (PHASE == 3) {  // o_t = inter . wo (reads old h + x/c, concurrent with MFMA reads)
      float s = 0.f;
      const int kbase = s8 * 68;
      for (int kk = 0; kk < 68; kk += 4) {
        uint2 u = *(const uint2*)&inter[row8 * ISTRIDE + kbase + kk];
        s += h2f(u.x & 0xffffu) * wo_lds[kbase + kk]
           + h2f(u.x >> 16)     * wo_lds[kbase + kk + 1]
           + h2f(u.y & 0xffffu) * wo_lds[kbase + kk + 2]
           + h2f(u.y >> 16)     * wo_lds[kbase + kk + 3];
      }
      s += __shfl_xor(s, 1);
      s += __shfl_xor(s, 2);
      s += __shfl_xor(s, 4);
      if (s8 == 0) out[(size_t)(b0 + row8) * T_ + t] = s;
    }
    __syncthreads();  // all reads of inter done
    // write h_{j+1} (C-layout -> inter A-layout)
    #pragma unroll
    for (int rt = 0; rt < 4; ++rt)
      for (int ct = 0; ct < 4; ++ct)
        for (int r = 0; r < 4; ++r) {
          int row = rt * 16 + q * 4 + r;
          int col = c0 + ct * 16 + l15;
          inter[row * ISTRIDE + col] = f2h(acc[rt][ct][r]);
        }
    if (j + 1 < KS) {  // stage x/c for next step
      int t2 = t + 1;
      const float* xp = x + ((size_t)(b0 + row8) * T_ + t2) * 16 + s8 * 2;
      float2 xv = *(const float2*)xp;
      unsigned u = (unsigned)f2h(xv.x) | ((unsigned)f2h(xv.y) << 16);
      *(unsigned*)&inter[row8 * ISTRIDE + 512 + s8 * 2] = u;
      if (tid < 64) inter[tid * ISTRIDE + 528] = f2h(cost[(size_t)(b0 + tid) * T_ + t2]);
    }
  }
  __syncthreads();
  if (PHASE == 1) {
    unsigned short* vp = Vdst + ((size_t)i_blk * 256 + b0 + row8) * 512;
    for (int nn = 0; nn < 64; nn += 8) {
      int n = s8 * 64 + nn;
      *(uint4*)(vp + n) = *(const uint4*)&inter[row8 * ISTRIDE + n];
    }
  } else if (i_blk == NB - 1) {  // h_final
    float* hp = out + (size_t)B_ * T_ + (size_t)(b0 + row8) * 512;
    for (int nn = 0; nn < 64; nn += 2) {
      int n = s8 * 64 + nn;
      unsigned u = *(const unsigned*)&inter[row8 * ISTRIDE + n];
      hp[n] = h2f(u & 0xffffu);
      hp[n + 1] = h2f(u >> 16);
    }
  }
}

extern "C" void kernel_launch(void* const* d_in, const int* in_sizes, int n_in,
                              void* d_out, int out_size, void* d_ws, size_t ws_size,
                              hipStream_t stream) {
  (void)in_sizes; (void)n_in; (void)out_size; (void)ws_size;
  const float* x      = (const float*)d_in[0];
  const float* hidden = (const float*)d_in[1];
  const float* cost   = (const float*)d_in[2];
  const float* Wo     = (const float*)d_in[3];
  const float* Wh     = (const float*)d_in[4];
  float* out = (float*)d_out;
  char* ws = (char*)d_ws;

  unsigned short* WfT = (unsigned short*)ws;           // 557056 B
  char* pow_base = ws + 557056;                        // 11 x 1MB (plain+t32 per level)
  unsigned short* V0 = (unsigned short*)(ws + 557056 + 11ull * 1048576);  // 16.78 MB
  unsigned short* V1 = V0 + (size_t)NB * 256 * 512;                       // 16.78 MB

  auto powP = [&](int l) { return (unsigned short*)(pow_base + (size_t)l * 1048576); };
  auto powT = [&](int l) { return (unsigned short*)(pow_base + (size_t)l * 1048576 + 524288); };

  prep_kernel<<<2112, 256, 0, stream>>>(Wh, WfT, powP(0), powT(0));
  for (int l = 1; l <= 10; ++l)  // M^(2^l), l=5..10 used by scan (M^32..M^1024)
    sq_kernel<<<8, 512, 0, stream>>>(powP(l - 1), powT(l - 1), powP(l), powT(l));
  chunk_kernel<1><<<256, 512, 0, stream>>>(x, hidden, cost, Wo, WfT, nullptr, V0, nullptr);
  for (int r = 0; r < 6; ++r) {
    unsigned short* src = (r & 1) ? V1 : V0;
    unsigned short* dst = (r & 1) ? V0 : V1;
    scan_kernel<<<256, 512, 0, stream>>>(src, dst, powT(5 + r), 1 << r);
  }
  // after 6 rounds the inclusive scan (block-end states P_i) is in V0
  chunk_kernel<3><<<256, 512, 0, stream>>>(x, hidden, cost, Wo, WfT, V0, nullptr, out);
}

// Round 4
// 541.974 us; speedup vs baseline: 2.7069x; 2.7069x over previous
//
#include <hip/hip_runtime.h>

// Linear-RNN via pure GEMM decomposition (no per-step loop at all).
//   h_{t+1} = h_t@M + x̄_t@S ;  o_t = x̄_t·wod + h_t·woh
//   chunk KS=128, NB=16:
//   v_i   = A_i @ W̃            (W̃[s*17+q] = (S@M^{127-s})[q], log-doubled Q-stack)
//   o     = A_i @ T + P_{i-1}@G (T Toeplitz from ā_λ=S@M^λ@woh; diag = wod; G=[M^j woh])
//   P_i   = inclusive scan of v with M^128 powers (4 Hillis-Steele rounds)
// All GEMMs fp16 in / fp32 accum.
// R3 fix: Qs rows [0,17) = Q_0 = S were never initialized (read 0xAA poison);
// prep now seeds them alongside Sr. Everything else unchanged.

typedef __attribute__((ext_vector_type(8))) _Float16 half8;
typedef __attribute__((ext_vector_type(4))) float f32x4;
typedef unsigned short u16;

#define KS 128
#define NBK 16
#define KTOT 2176   // KS*17
#define KCN_BIG 68  // KTOT/32
#define NBIG 640    // 512 V cols + 128 conv cols
#define ROWS 4096   // 256 batch * 16 chunks, row = i*256 + b

__device__ __forceinline__ u16 f2h(float f) {
  union { _Float16 h; u16 u; } v; v.h = (_Float16)f; return v.u;
}
__device__ __forceinline__ float h2f(u16 u) {
  union { u16 u; _Float16 h; } v; v.u = u; return (float)v.h;
}

// wave computes 64 rows x 64 cols; A plain fp16 (lda), B in T32 layout [kc][nstr][32].
__device__ __forceinline__ void wave_gemm64(const u16* __restrict__ A, int lda,
                                            const u16* __restrict__ Bt, int nstr,
                                            int kcN, int c0, int lane,
                                            f32x4 (&acc)[4][4]) {
  const int q = lane >> 4, l15 = lane & 15;
  #pragma unroll
  for (int rt = 0; rt < 4; ++rt)
    #pragma unroll
    for (int ct = 0; ct < 4; ++ct) { f32x4 z = {0.f,0.f,0.f,0.f}; acc[rt][ct] = z; }
  for (int kc = 0; kc < kcN; ++kc) {
    half8 a[4], b[4];
    #pragma unroll
    for (int rt = 0; rt < 4; ++rt)
      a[rt] = *(const half8*)(A + (size_t)(rt*16 + l15)*lda + kc*32 + q*8);
    #pragma unroll
    for (int ct = 0; ct < 4; ++ct)
      b[ct] = *(const half8*)(Bt + (size_t)kc*nstr*32 + (c0 + ct*16 + l15)*32 + q*8);
    #pragma unroll
    for (int rt = 0; rt < 4; ++rt)
      #pragma unroll
      for (int ct = 0; ct < 4; ++ct)
        acc[rt][ct] = __builtin_amdgcn_mfma_f32_16x16x32_f16(a[rt], b[ct], acc[rt][ct], 0,0,0);
  }
}

// ---- prep: M (plain+T32), S_r (+ seed Qs lag-0), G col0, wod, hidden->fp16 ----
__global__ void prep_kernel(const float* __restrict__ Wh, const float* __restrict__ Wo,
                            const float* __restrict__ hidden,
                            u16* __restrict__ Mp0, u16* __restrict__ Mt0,
                            u16* __restrict__ Sr, float* __restrict__ G,
                            float* __restrict__ wod, u16* __restrict__ Hf,
                            u16* __restrict__ Qs) {
  int idx = blockIdx.x * 256 + threadIdx.x;
  if (idx < 262144) {                       // M[k][n] = Wh[n][16+k]
    int k = idx >> 9, n = idx & 511;
    u16 v = f2h(Wh[n*529 + 16 + k]);
    Mp0[k*512 + n] = v;
    Mt0[(k>>5)*16384 + n*32 + (k&31)] = v;
    return;
  }
  idx -= 262144;
  if (idx < 8704) {                         // S_r[q][n]; Qs row q = Q_0[q] = S[q]
    int q = idx >> 9, n = idx & 511;
    u16 v = f2h(Wh[n*529 + (q < 16 ? q : 528)]);
    Sr[idx] = v;
    Qs[idx] = v;                            // R3 fix: seed Q-stack lag 0
    return;
  }
  idx -= 8704;
  if (idx < 512) { G[idx*128 + 0] = Wo[16 + idx]; return; }   // g_0 = woh
  idx -= 512;
  if (idx < 17) { wod[idx] = Wo[idx < 16 ? idx : 528]; return; }
  idx -= 17;
  if (idx < 131072) Hf[idx] = f2h(hidden[idx]);
}

// ---- level l: sq M^(2^l)->M^(2^(l+1)); append Q lags [m,2m); append G cols [m,2m) ----
__global__ __launch_bounds__(256) void level_kernel(
    const u16* __restrict__ Mp_in, const u16* __restrict__ Mt_in,
    u16* __restrict__ Mp_out, u16* __restrict__ Mt_out,
    u16* __restrict__ Qs, float* __restrict__ G, int l) {
  const int m = 1 << l;
  const int nq = (17*m + 63) >> 6;
  const int tid = threadIdx.x, bx = blockIdx.x;
  const int wid = tid >> 6, lane = tid & 63, q = lane >> 4, l15 = lane & 15;

  if (bx < 16) {  // square: 64r x 256c per WG (4 waves)
    int rowg = bx >> 1, colg = bx & 1;
    int row0 = rowg*64, c0 = colg*256 + wid*64;
    f32x4 acc[4][4];
    wave_gemm64(Mp_in + row0*512, 512, Mt_in, 512, 16, c0, lane, acc);
    #pragma unroll
    for (int rt = 0; rt < 4; ++rt)
      for (int ct = 0; ct < 4; ++ct)
        for (int r = 0; r < 4; ++r) {
          int row = row0 + rt*16 + q*4 + r, col = c0 + ct*16 + l15;
          u16 v = f2h(acc[rt][ct][r]);
          Mp_out[row*512 + col] = v;
          Mt_out[(row>>5)*16384 + col*32 + (row&31)] = v;
        }
    return;
  }
  int bq = bx - 16;
  if (bq < 2*nq) {  // Q append: rows [0,17m) @ M^m -> rows [17m, 34m)
    int qrowg = bq >> 1, colg = bq & 1;
    int row0 = qrowg*64, c0 = colg*256 + wid*64;
    f32x4 acc[4][4];
    wave_gemm64(Qs + (size_t)row0*512, 512, Mt_in, 512, 16, c0, lane, acc);
    int lim = 17*m;
    #pragma unroll
    for (int rt = 0; rt < 4; ++rt)
      for (int ct = 0; ct < 4; ++ct)
        for (int r = 0; r < 4; ++r) {
          int rowIn = row0 + rt*16 + q*4 + r, col = c0 + ct*16 + l15;
          if (rowIn < lim) Qs[(size_t)(lim + rowIn)*512 + col] = f2h(acc[rt][ct][r]);
        }
    return;
  }
  int bg = bq - 2*nq;  // G append: G[:, m+c] = M^m @ G[:, c], c<m ; 32 WGs x 16 n-rows
  int n0 = bg * 16;
  for (int idx = tid; idx < 16*m; idx += 256) {
    int c = idx & (m - 1), n = n0 + (idx >> l);
    float s = 0.f;
    const u16* mrow = Mp_in + n*512;
    for (int k = 0; k < 512; ++k) s += h2f(mrow[k]) * G[k*128 + c];
    G[n*128 + m + c] = s;
  }
}

// ---- Cb[q][lam] = sum_k Sr[q][k] * G[k][lam] ----
__global__ void cbar_kernel(const u16* __restrict__ Sr, const float* __restrict__ G,
                            float* __restrict__ Cb) {
  int qq = blockIdx.x, lam = threadIdx.x;
  float s = 0.f;
  for (int k = 0; k < 512; ++k) s += h2f(Sr[qq*512 + k]) * G[k*128 + lam];
  Cb[qq*128 + lam] = s;
}

// ---- build B (T32, 640 cols): cols<512 = W-tilde from Qstack; cols>=512 = Toeplitz T.
//      also build Gt (T32 of G). ----
__global__ void bbuild_kernel(const u16* __restrict__ Qs, const float* __restrict__ Cb,
                              const float* __restrict__ wod, const float* __restrict__ G,
                              u16* __restrict__ Bt, u16* __restrict__ Gt) {
  int idx = blockIdx.x * 256 + threadIdx.x;
  if (idx < KTOT * NBIG) {
    int krow = idx / NBIG, n = idx - krow * NBIG;
    int kc = krow >> 5, kk = krow & 31;
    int s = krow / 17, qq = krow - s * 17;
    u16 v;
    if (n < 512) {
      v = Qs[(size_t)((127 - s)*17 + qq)*512 + n];
    } else {
      int j = n - 512;
      if (s < j)       v = f2h(Cb[qq*128 + (j - 1 - s)]);
      else if (s == j) v = f2h(wod[qq]);
      else             v = 0;
    }
    Bt[(size_t)kc*(NBIG*32) + n*32 + kk] = v;
    return;
  }
  idx -= KTOT * NBIG;
  if (idx < 512*128) {
    int k = idx >> 7, j = idx & 127;
    Gt[(k>>5)*4096 + j*32 + (k&31)] = f2h(G[k*128 + j]);
  }
}

// ---- A[r = i*256+b][s*17+q] = x-bar fp16 ----
__global__ void abuild_kernel(const float* __restrict__ x, const float* __restrict__ cost,
                              u16* __restrict__ A) {
  int r = blockIdx.x, s = threadIdx.x;
  int i = r >> 8, b = r & 255;
  int t = i*128 + s;
  const float* xp = x + ((size_t)b*2048 + t)*16;
  u16* ap = A + (size_t)r*KTOT + s*17;
  #pragma unroll
  for (int p = 0; p < 16; p += 4) {
    float4 v = *(const float4*)(xp + p);
    ap[p] = f2h(v.x); ap[p+1] = f2h(v.y); ap[p+2] = f2h(v.z); ap[p+3] = f2h(v.w);
  }
  ap[16] = f2h(cost[(size_t)b*2048 + t]);
}

// ---- big GEMM [4096 x 640 x 2176]: cols<512 -> V0 fp16; cols>=512 -> out fp32 (conv o) ----
__global__ __launch_bounds__(256) void biggemm_kernel(const u16* __restrict__ A,
                                                      const u16* __restrict__ Bt,
                                                      u16* __restrict__ V0,
                                                      float* __restrict__ out) {
  int colg = blockIdx.x >> 5, rowg = blockIdx.x & 31;
  const int tid = threadIdx.x, wid = tid >> 6, lane = tid & 63;
  const int q = lane >> 4, l15 = lane & 15;
  int wrow = wid >> 1, wcol = wid & 1;
  int row0 = rowg*128 + wrow*64, c0 = colg*128 + wcol*64;
  f32x4 acc[4][4];
  wave_gemm64(A + (size_t)row0*KTOT, KTOT, Bt, NBIG, KCN_BIG, c0, lane, acc);
  #pragma unroll
  for (int rt = 0; rt < 4; ++rt)
    for (int ct = 0; ct < 4; ++ct)
      for (int r = 0; r < 4; ++r) {
        int rg = row0 + rt*16 + q*4 + r, col = c0 + ct*16 + l15;
        if (col < 512) {
          V0[(size_t)rg*512 + col] = f2h(acc[rt][ct][r]);
        } else {
          int j = col - 512, b = rg & 255, i = rg >> 8;
          out[(size_t)b*2048 + i*128 + j] = acc[rt][ct][r];
        }
      }
}

// ---- inject: V0[block 0] += Hf @ M^128 ----
__global__ __launch_bounds__(256) void inject_kernel(const u16* __restrict__ Hf,
                                                     const u16* __restrict__ Mt7,
                                                     u16* __restrict__ V0) {
  int rowg = blockIdx.x >> 1, colg = blockIdx.x & 1;
  const int tid = threadIdx.x, wid = tid >> 6, lane = tid & 63;
  const int q = lane >> 4, l15 = lane & 15;
  int row0 = rowg*64, c0 = colg*256 + wid*64;
  f32x4 acc[4][4];
  wave_gemm64(Hf + (size_t)row0*512, 512, Mt7, 512, 16, c0, lane, acc);
  #pragma unroll
  for (int rt = 0; rt < 4; ++rt)
    for (int ct = 0; ct < 4; ++ct)
      for (int r = 0; r < 4; ++r) {
        int rg = row0 + rt*16 + q*4 + r, col = c0 + ct*16 + l15;
        size_t o = (size_t)rg*512 + col;
        V0[o] = f2h(h2f(V0[o]) + acc[rt][ct][r]);
      }
}

// ---- scan round: Vdst[i] = Vsrc[i-d]@M^(128d) + Vsrc[i] (i>=d) else copy ----
__global__ __launch_bounds__(256) void scan_kernel(const u16* __restrict__ Vsrc,
                                                   u16* __restrict__ Vdst,
                                                   const u16* __restrict__ Mt, int d) {
  int bx = blockIdx.x;
  int i = bx >> 3, rowg = (bx >> 1) & 3, colg = bx & 1;
  const int tid = threadIdx.x, wid = tid >> 6, lane = tid & 63;
  const int q = lane >> 4, l15 = lane & 15;
  int row0 = rowg*64;
  if (i >= d) {
    int c0 = colg*256 + wid*64;
    f32x4 acc[4][4];
    wave_gemm64(Vsrc + (size_t)((i-d)*256 + row0)*512, 512, Mt, 512, 16, c0, lane, acc);
    #pragma unroll
    for (int rt = 0; rt < 4; ++rt)
      for (int ct = 0; ct < 4; ++ct)
        for (int r = 0; r < 4; ++r) {
          int rg = i*256 + row0 + rt*16 + q*4 + r, col = c0 + ct*16 + l15;
          Vdst[(size_t)rg*512 + col] = f2h(acc[rt][ct][r] + h2f(Vsrc[(size_t)rg*512 + col]));
        }
  } else {
    for (int it = tid; it < 64*32; it += 256) {
      int rl = it >> 5, cu = it & 31;
      size_t o = (size_t)(i*256 + row0 + rl)*512 + colg*256 + cu*8;
      *(uint4*)(Vdst + o) = *(const uint4*)(Vsrc + o);
    }
  }
}

// ---- final: out[b][i*128+j] += Pprev[(i,b)] . g_j ----
__global__ __launch_bounds__(128) void final_kernel(const u16* __restrict__ V0,
                                                    const u16* __restrict__ Hf,
                                                    const u16* __restrict__ Gt,
                                                    float* __restrict__ out) {
  int row0 = blockIdx.x * 64;
  const int tid = threadIdx.x, wid = tid >> 6, lane = tid & 63;
  const int q = lane >> 4, l15 = lane & 15;
  int c0 = wid * 64;
  const u16* Abase = (row0 < 256) ? (Hf + (size_t)row0*512) : (V0 + (size_t)(row0-256)*512);
  f32x4 acc[4][4];
  wave_gemm64(Abase, 512, Gt, 128, 16, c0, lane, acc);
  #pragma unroll
  for (int rt = 0; rt < 4; ++rt)
    for (int ct = 0; ct < 4; ++ct)
      for (int r = 0; r < 4; ++r) {
        int rg = row0 + rt*16 + q*4 + r, j = c0 + ct*16 + l15;
        int b = rg & 255, i = rg >> 8;
        size_t o = (size_t)b*2048 + i*128 + j;
        out[o] += acc[rt][ct][r];
      }
}

// ---- h_final = P_15 ----
__global__ void hfinal_kernel(const u16* __restrict__ V0, float* __restrict__ out) {
  int idx = blockIdx.x * 256 + threadIdx.x;
  if (idx < 131072)
    out[524288 + idx] = h2f(V0[(size_t)(3840 + (idx >> 9))*512 + (idx & 511)]);
}

extern "C" void kernel_launch(void* const* d_in, const int* in_sizes, int n_in,
                              void* d_out, int out_size, void* d_ws, size_t ws_size,
                              hipStream_t stream) {
  (void)in_sizes; (void)n_in; (void)out_size; (void)ws_size;
  const float* x      = (const float*)d_in[0];
  const float* hidden = (const float*)d_in[1];
  const float* cost   = (const float*)d_in[2];
  const float* Wo     = (const float*)d_in[3];
  const float* Wh     = (const float*)d_in[4];
  float* out = (float*)d_out;
  char* ws = (char*)d_ws;

  auto Mp = [&](int l){ return (u16*)(ws + (size_t)l*524288); };
  auto Mt = [&](int l){ return (u16*)(ws + 5767168 + (size_t)l*524288); };
  u16*   Qs  = (u16*)(ws + 11534336);   // 2176 x 512
  float* G   = (float*)(ws + 13762560); // 512 x 128
  u16*   Sr  = (u16*)(ws + 14024704);   // 17 x 512
  float* wod = (float*)(ws + 14057472); // 17
  float* Cb  = (float*)(ws + 14057728); // 17 x 128
  u16*   Hf  = (u16*)(ws + 14074112);   // 256 x 512
  u16*   Bt  = (u16*)(ws + 14336256);   // T32 2176 x 640
  u16*   Gt  = (u16*)(ws + 17121536);   // T32 512 x 128
  u16*   A   = (u16*)(ws + 17252608);   // 4096 x 2176
  u16*   V0  = (u16*)(ws + 35078400);   // 4096 x 512
  u16*   V1  = (u16*)(ws + 39272704);   // 4096 x 512

  prep_kernel<<<1573, 256, 0, stream>>>(Wh, Wo, hidden, Mp(0), Mt(0), Sr, G, wod, Hf, Qs);
  for (int l = 0; l <= 9; ++l) {
    int m = 1 << l;
    int nq = (17*m + 63) >> 6;
    int grid = (l <= 6) ? (16 + 2*nq + 32) : 16;
    level_kernel<<<grid, 256, 0, stream>>>(Mp(l), Mt(l), Mp(l+1), Mt(l+1), Qs, G, l);
  }
  cbar_kernel<<<17, 128, 0, stream>>>(Sr, G, Cb);
  bbuild_kernel<<<(KTOT*NBIG + 512*128 + 255)/256, 256, 0, stream>>>(Qs, Cb, wod, G, Bt, Gt);
  abuild_kernel<<<ROWS, 128, 0, stream>>>(x, cost, A);
  biggemm_kernel<<<160, 256, 0, stream>>>(A, Bt, V0, out);
  inject_kernel<<<8, 256, 0, stream>>>(Hf, Mt(7), V0);
  scan_kernel<<<128, 256, 0, stream>>>(V0, V1, Mt(7), 1);
  scan_kernel<<<128, 256, 0, stream>>>(V1, V0, Mt(8), 2);
  scan_kernel<<<128, 256, 0, stream>>>(V0, V1, Mt(9), 4);
  scan_kernel<<<128, 256, 0, stream>>>(V1, V0, Mt(10), 8);
  final_kernel<<<64, 128, 0, stream>>>(V0, Hf, Gt, out);
  hfinal_kernel<<<512, 256, 0, stream>>>(V0, out);
}

// Round 5
// 443.284 us; speedup vs baseline: 3.3096x; 1.2226x over previous
//
#include <hip/hip_runtime.h>

// Linear-RNN via pure GEMM decomposition (no per-step loop).
//   h_{t+1} = h_t@M + x̄_t@S ;  o_t = x̄_t·wod + h_t·woh
//   chunk KS=128, NB=16:
//   v_i   = A_i @ W̃            (W̃[s*17+q] = (S@M^{127-s})[q], log-doubled Q-stack)
//   o     = A_i @ T + P_{i-1}@G (T Toeplitz from ā_λ=S@M^λ@woh; diag = wod; G=[M^j woh])
//   P_i   = inclusive scan of v with M^128 powers (4 Hillis-Steele rounds;
//           hidden h0 fused as virtual block -1 -> no inject kernel)
// All GEMMs fp16 in / fp32 accum. R5: 64x16 wave tiles (grid 4x larger),
// fused prep+abuild / inject->scan / hfinal->final, 4-acc unrolled dot chains.

typedef __attribute__((ext_vector_type(8))) _Float16 half8;
typedef __attribute__((ext_vector_type(4))) float f32x4;
typedef unsigned short u16;

#define KTOT 2176   // 128*17
#define KCN_BIG 68  // KTOT/32
#define NBIG 640    // 512 V cols + 128 conv cols

__device__ __forceinline__ u16 f2h(float f) {
  union { _Float16 h; u16 u; } v; v.h = (_Float16)f; return v.u;
}
__device__ __forceinline__ float h2f(u16 u) {
  union { u16 u; _Float16 h; } v; v.u = u; return (float)v.h;
}

// wave computes 64 rows x 16 cols; A plain fp16 (lda), B in T32 layout [kc][nstr][32].
__device__ __forceinline__ void wave_gemm64x16(const u16* __restrict__ A, int lda,
                                               const u16* __restrict__ Bt, int nstr,
                                               int kcN, int c0, int lane,
                                               f32x4 (&acc)[4]) {
  const int q = lane >> 4, l15 = lane & 15;
  #pragma unroll
  for (int rt = 0; rt < 4; ++rt) { f32x4 z = {0.f,0.f,0.f,0.f}; acc[rt] = z; }
  for (int kc = 0; kc < kcN; ++kc) {
    half8 a[4];
    half8 b = *(const half8*)(Bt + (size_t)kc*nstr*32 + (c0 + l15)*32 + q*8);
    #pragma unroll
    for (int rt = 0; rt < 4; ++rt)
      a[rt] = *(const half8*)(A + (size_t)(rt*16 + l15)*lda + kc*32 + q*8);
    #pragma unroll
    for (int rt = 0; rt < 4; ++rt)
      acc[rt] = __builtin_amdgcn_mfma_f32_16x16x32_f16(a[rt], b, acc[rt], 0,0,0);
  }
}

// ---- fused prep + A-build ----
__global__ __launch_bounds__(256) void prep_abuild_kernel(
    const float* __restrict__ x, const float* __restrict__ cost,
    const float* __restrict__ Wh, const float* __restrict__ Wo,
    const float* __restrict__ hidden,
    u16* __restrict__ A,
    u16* __restrict__ Mp0, u16* __restrict__ Mt0,
    u16* __restrict__ Sr, float* __restrict__ G,
    float* __restrict__ wod, u16* __restrict__ Hf, u16* __restrict__ Qs) {
  const int bx = blockIdx.x, tid = threadIdx.x;
  if (bx < 2048) {                          // A[r][s*17+q] = x-bar fp16 (2 rows/WG)
    int r = bx*2 + (tid >> 7), s = tid & 127;
    int i = r >> 8, b = r & 255, t = i*128 + s;
    const float* xp = x + ((size_t)b*2048 + t)*16;
    u16* ap = A + (size_t)r*KTOT + s*17;
    #pragma unroll
    for (int p = 0; p < 16; p += 4) {
      float4 v = *(const float4*)(xp + p);
      ap[p] = f2h(v.x); ap[p+1] = f2h(v.y); ap[p+2] = f2h(v.z); ap[p+3] = f2h(v.w);
    }
    ap[16] = f2h(cost[(size_t)b*2048 + t]);
    return;
  }
  int idx = (bx - 2048)*256 + tid;
  if (idx < 262144) {                       // M[k][n] = Wh[n][16+k]
    int k = idx >> 9, n = idx & 511;
    u16 v = f2h(Wh[n*529 + 16 + k]);
    Mp0[k*512 + n] = v;
    Mt0[(k>>5)*16384 + n*32 + (k&31)] = v;
    return;
  }
  idx -= 262144;
  if (idx < 8704) {                         // S_r[q][n]; Qs lag-0 seed
    int q = idx >> 9, n = idx & 511;
    u16 v = f2h(Wh[n*529 + (q < 16 ? q : 528)]);
    Sr[idx] = v;
    Qs[idx] = v;
    return;
  }
  idx -= 8704;
  if (idx < 512) { G[idx*128 + 0] = Wo[16 + idx]; return; }   // g_0 = woh
  idx -= 512;
  if (idx < 17) { wod[idx] = Wo[idx < 16 ? idx : 528]; return; }
  idx -= 17;
  if (idx < 131072) Hf[idx] = f2h(hidden[idx]);
}

// ---- level l: sq M^(2^l)->M^(2^(l+1)); append Q lags [m,2m); append G cols [m,2m) ----
__global__ __launch_bounds__(256) void level_kernel(
    const u16* __restrict__ Mp_in, const u16* __restrict__ Mt_in,
    u16* __restrict__ Mp_out, u16* __restrict__ Mt_out,
    u16* __restrict__ Qs, float* __restrict__ G, int l) {
  const int m = 1 << l;
  const int nq = (17*m + 63) >> 6;
  const int tid = threadIdx.x, bx = blockIdx.x;
  const int wid = tid >> 6, lane = tid & 63, q = lane >> 4, l15 = lane & 15;

  if (bx < 64) {  // square: 64r x 64c per WG, wave 64x16
    int rowg = bx >> 3, colg = bx & 7;
    int row0 = rowg*64, c0 = colg*64 + wid*16;
    f32x4 acc[4];
    wave_gemm64x16(Mp_in + row0*512, 512, Mt_in, 512, 16, c0, lane, acc);
    #pragma unroll
    for (int rt = 0; rt < 4; ++rt)
      for (int r = 0; r < 4; ++r) {
        int row = row0 + rt*16 + q*4 + r, col = c0 + l15;
        u16 v = f2h(acc[rt][r]);
        Mp_out[row*512 + col] = v;
        Mt_out[(row>>5)*16384 + col*32 + (row&31)] = v;
      }
    return;
  }
  int bq = bx - 64;
  if (bq < nq*8) {  // Q append: rows [0,17m) @ M^m -> rows [17m, 34m)
    int qrowg = bq >> 3, colg = bq & 7;
    int row0 = qrowg*64, c0 = colg*64 + wid*16;
    f32x4 acc[4];
    wave_gemm64x16(Qs + (size_t)row0*512, 512, Mt_in, 512, 16, c0, lane, acc);
    int lim = 17*m;
    #pragma unroll
    for (int rt = 0; rt < 4; ++rt)
      for (int r = 0; r < 4; ++r) {
        int rowIn = row0 + rt*16 + q*4 + r, col = c0 + l15;
        if (rowIn < lim) Qs[(size_t)(lim + rowIn)*512 + col] = f2h(acc[rt][r]);
      }
    return;
  }
  int bg = bq - nq*8;  // G append: G[:, m+c] = M^m @ G[:, c], c<m ; 32 WGs x 16 n-rows
  int n0 = bg * 16;
  for (int idx = tid; idx < 16*m; idx += 256) {
    int c = idx & (m - 1), n = n0 + (idx >> l);
    const u16* mrow = Mp_in + n*512;
    float s0 = 0.f, s1 = 0.f, s2 = 0.f, s3 = 0.f;
    for (int k = 0; k < 512; k += 4) {
      s0 += h2f(mrow[k])   * G[k*128 + c];
      s1 += h2f(mrow[k+1]) * G[(k+1)*128 + c];
      s2 += h2f(mrow[k+2]) * G[(k+2)*128 + c];
      s3 += h2f(mrow[k+3]) * G[(k+3)*128 + c];
    }
    G[n*128 + m + c] = (s0 + s1) + (s2 + s3);
  }
}

// ---- Cb[q][lam] = sum_k Sr[q][k] * G[k][lam] ----
__global__ void cbar_kernel(const u16* __restrict__ Sr, const float* __restrict__ G,
                            float* __restrict__ Cb) {
  int qq = blockIdx.x, lam = threadIdx.x;
  float s0 = 0.f, s1 = 0.f, s2 = 0.f, s3 = 0.f;
  for (int k = 0; k < 512; k += 4) {
    s0 += h2f(Sr[qq*512 + k])   * G[k*128 + lam];
    s1 += h2f(Sr[qq*512 + k+1]) * G[(k+1)*128 + lam];
    s2 += h2f(Sr[qq*512 + k+2]) * G[(k+2)*128 + lam];
    s3 += h2f(Sr[qq*512 + k+3]) * G[(k+3)*128 + lam];
  }
  Cb[qq*128 + lam] = (s0 + s1) + (s2 + s3);
}

// ---- build B (T32, 640 cols) + Gt (T32 of G) ----
__global__ void bbuild_kernel(const u16* __restrict__ Qs, const float* __restrict__ Cb,
                              const float* __restrict__ wod, const float* __restrict__ G,
                              u16* __restrict__ Bt, u16* __restrict__ Gt) {
  int idx = blockIdx.x * 256 + threadIdx.x;
  if (idx < KTOT * NBIG) {
    int krow = idx / NBIG, n = idx - krow * NBIG;
    int kc = krow >> 5, kk = krow & 31;
    int s = krow / 17, qq = krow - s * 17;
    u16 v;
    if (n < 512) {
      v = Qs[(size_t)((127 - s)*17 + qq)*512 + n];
    } else {
      int j = n - 512;
      if (s < j)       v = f2h(Cb[qq*128 + (j - 1 - s)]);
      else if (s == j) v = f2h(wod[qq]);
      else             v = 0;
    }
    Bt[(size_t)kc*(NBIG*32) + n*32 + kk] = v;
    return;
  }
  idx -= KTOT * NBIG;
  if (idx < 512*128) {
    int k = idx >> 7, j = idx & 127;
    Gt[(k>>5)*4096 + j*32 + (k&31)] = f2h(G[k*128 + j]);
  }
}

// ---- big GEMM [4096 x 640 x 2176]: cols<512 -> V0 fp16; cols>=512 -> out fp32 ----
__global__ __launch_bounds__(256) void biggemm_kernel(const u16* __restrict__ A,
                                                      const u16* __restrict__ Bt,
                                                      u16* __restrict__ V0,
                                                      float* __restrict__ out) {
  // bx = colg*64 + rowg  (consecutive bx = same colg -> same-XCD A reuse)
  int colg = blockIdx.x >> 6, rowg = blockIdx.x & 63;
  const int tid = threadIdx.x, wid = tid >> 6, lane = tid & 63;
  const int q = lane >> 4, l15 = lane & 15;
  int row0 = rowg*64, c0 = colg*64 + wid*16;
  f32x4 acc[4];
  wave_gemm64x16(A + (size_t)row0*KTOT, KTOT, Bt, NBIG, KCN_BIG, c0, lane, acc);
  #pragma unroll
  for (int rt = 0; rt < 4; ++rt)
    for (int r = 0; r < 4; ++r) {
      int rg = row0 + rt*16 + q*4 + r, col = c0 + l15;
      if (col < 512) {
        V0[(size_t)rg*512 + col] = f2h(acc[rt][r]);
      } else {
        int j = col - 512, b = rg & 255, i = rg >> 8;
        out[(size_t)b*2048 + i*128 + j] = acc[rt][r];
      }
    }
}

// ---- scan round: Vdst[i] = Vsrc[i-d]@M^(128d) + Vsrc[i]; i-d==-1 uses Hf ----
__global__ __launch_bounds__(256) void scan_kernel(const u16* __restrict__ Vsrc,
                                                   u16* __restrict__ Vdst,
                                                   const u16* __restrict__ Mt,
                                                   const u16* __restrict__ Hf, int d) {
  int bx = blockIdx.x;
  int i = bx >> 5, rowg = (bx >> 3) & 3, colg = bx & 7;
  const int tid = threadIdx.x, wid = tid >> 6, lane = tid & 63;
  const int q = lane >> 4, l15 = lane & 15;
  int row0 = rowg*64;
  int src_i = i - d;
  if (src_i >= -1) {
    const u16* Asrc = (src_i >= 0) ? Vsrc + (size_t)(src_i*256 + row0)*512
                                   : Hf + (size_t)row0*512;
    int c0 = colg*64 + wid*16;
    f32x4 acc[4];
    wave_gemm64x16(Asrc, 512, Mt, 512, 16, c0, lane, acc);
    #pragma unroll
    for (int rt = 0; rt < 4; ++rt)
      for (int r = 0; r < 4; ++r) {
        int rg = i*256 + row0 + rt*16 + q*4 + r, col = c0 + l15;
        Vdst[(size_t)rg*512 + col] = f2h(acc[rt][r] + h2f(Vsrc[(size_t)rg*512 + col]));
      }
  } else {
    for (int it = tid; it < 512; it += 256) {
      int rl = it >> 3, cu = it & 7;
      size_t o = (size_t)(i*256 + row0 + rl)*512 + colg*64 + cu*8;
      *(uint4*)(Vdst + o) = *(const uint4*)(Vsrc + o);
    }
  }
}

// ---- final: out[b][i*128+j] += Pprev[(i,b)].g_j ; plus h_final = P_15 copy ----
__global__ __launch_bounds__(256) void final_kernel(const u16* __restrict__ V0,
                                                    const u16* __restrict__ Hf,
                                                    const u16* __restrict__ Gt,
                                                    float* __restrict__ out) {
  const int bx = blockIdx.x, tid = threadIdx.x;
  if (bx >= 128) {  // h_final = P_15
    int idx = (bx - 128)*256 + tid;
    int base = idx * 8;
    int row = 3840 + (base >> 9), col = base & 511;
    const u16* vp = V0 + (size_t)row*512 + col;
    float* hp = out + 524288 + base;
    #pragma unroll
    for (int e = 0; e < 8; ++e) hp[e] = h2f(vp[e]);
    return;
  }
  int rowg = bx >> 1, colg = bx & 1;
  const int wid = tid >> 6, lane = tid & 63;
  const int q = lane >> 4, l15 = lane & 15;
  int row0 = rowg*64, c0 = colg*64 + wid*16;
  const u16* Abase = (row0 < 256) ? (Hf + (size_t)row0*512) : (V0 + (size_t)(row0-256)*512);
  f32x4 acc[4];
  wave_gemm64x16(Abase, 512, Gt, 128, 16, c0, lane, acc);
  #pragma unroll
  for (int rt = 0; rt < 4; ++rt)
    for (int r = 0; r < 4; ++r) {
      int rg = row0 + rt*16 + q*4 + r, j = c0 + l15;
      int b = rg & 255, i = rg >> 8;
      out[(size_t)b*2048 + i*128 + j] += acc[rt][r];
    }
}

extern "C" void kernel_launch(void* const* d_in, const int* in_sizes, int n_in,
                              void* d_out, int out_size, void* d_ws, size_t ws_size,
                              hipStream_t stream) {
  (void)in_sizes; (void)n_in; (void)out_size; (void)ws_size;
  const float* x      = (const float*)d_in[0];
  const float* hidden = (const float*)d_in[1];
  const float* cost   = (const float*)d_in[2];
  const float* Wo     = (const float*)d_in[3];
  const float* Wh     = (const float*)d_in[4];
  float* out = (float*)d_out;
  char* ws = (char*)d_ws;

  auto Mp = [&](int l){ return (u16*)(ws + (size_t)l*524288); };
  auto Mt = [&](int l){ return (u16*)(ws + 5767168 + (size_t)l*524288); };
  u16*   Qs  = (u16*)(ws + 11534336);   // 2176 x 512
  float* G   = (float*)(ws + 13762560); // 512 x 128
  u16*   Sr  = (u16*)(ws + 14024704);   // 17 x 512
  float* wod = (float*)(ws + 14057472); // 17
  float* Cb  = (float*)(ws + 14057728); // 17 x 128
  u16*   Hf  = (u16*)(ws + 14074112);   // 256 x 512
  u16*   Bt  = (u16*)(ws + 14336256);   // T32 2176 x 640
  u16*   Gt  = (u16*)(ws + 17121536);   // T32 512 x 128
  u16*   A   = (u16*)(ws + 17252608);   // 4096 x 2176
  u16*   V0  = (u16*)(ws + 35078400);   // 4096 x 512
  u16*   V1  = (u16*)(ws + 39272704);   // 4096 x 512

  prep_abuild_kernel<<<3621, 256, 0, stream>>>(x, cost, Wh, Wo, hidden,
                                               A, Mp(0), Mt(0), Sr, G, wod, Hf, Qs);
  for (int l = 0; l <= 9; ++l) {
    int m = 1 << l;
    int nq = (17*m + 63) >> 6;
    int grid = (l <= 6) ? (64 + nq*8 + 32) : 64;
    level_kernel<<<grid, 256, 0, stream>>>(Mp(l), Mt(l), Mp(l+1), Mt(l+1), Qs, G, l);
  }
  cbar_kernel<<<17, 128, 0, stream>>>(Sr, G, Cb);
  bbuild_kernel<<<(KTOT*NBIG + 512*128 + 255)/256, 256, 0, stream>>>(Qs, Cb, wod, G, Bt, Gt);
  biggemm_kernel<<<640, 256, 0, stream>>>(A, Bt, V0, out);
  scan_kernel<<<512, 256, 0, stream>>>(V0, V1, Mt(7), Hf, 1);
  scan_kernel<<<512, 256, 0, stream>>>(V1, V0, Mt(8), Hf, 2);
  scan_kernel<<<512, 256, 0, stream>>>(V0, V1, Mt(9), Hf, 4);
  scan_kernel<<<512, 256, 0, stream>>>(V1, V0, Mt(10), Hf, 8);
  final_kernel<<<192, 256, 0, stream>>>(V0, Hf, Gt, out);
}

// Round 6
// 324.233 us; speedup vs baseline: 4.5248x; 1.3672x over previous
//
#include <hip/hip_runtime.h>

// Linear-RNN via pure GEMM decomposition (no per-step loop).
//   h_{t+1} = h_t@M + x̄_t@S ;  o_t = x̄_t·wod + h_t·woh
//   v_i = A_i @ W̃ ; o = A_i @ T + P_{i-1}@G ; P = scan(v, M^128 powers)
// R6: 64x64 wave tiles with in-WG K-split-4 + LDS fp32 reduce (wave0 epilogue);
// A-build fused into the serial level chain as filler WGs.

typedef __attribute__((ext_vector_type(8))) _Float16 half8;
typedef __attribute__((ext_vector_type(4))) float f32x4;
typedef unsigned short u16;

#define KTOT 2176   // 128*17
#define NBIG 640    // 512 V cols + 128 conv cols

__device__ __forceinline__ u16 f2h(float f) {
  union { _Float16 h; u16 u; } v; v.h = (_Float16)f; return v.u;
}
__device__ __forceinline__ float h2f(u16 u) {
  union { u16 u; _Float16 h; } v; v.u = u; return (float)v.h;
}

// wave: 64 rows x 64 cols over kc in [kc0,kc1). A pre-offset to row0 (lda elems),
// Bt pre-offset to col base (T32 layout [kc][n][32], panel stride nstr*32).
__device__ __forceinline__ void wave_gemm(const u16* __restrict__ A, int lda,
                                          const u16* __restrict__ Bt, int nstr,
                                          int kc0, int kc1, int lane,
                                          f32x4 (&acc)[4][4]) {
  const int q = lane >> 4, l15 = lane & 15;
  #pragma unroll
  for (int rt = 0; rt < 4; ++rt)
    #pragma unroll
    for (int ct = 0; ct < 4; ++ct) { f32x4 z = {0.f,0.f,0.f,0.f}; acc[rt][ct] = z; }
  for (int kc = kc0; kc < kc1; ++kc) {
    half8 a[4], b[4];
    #pragma unroll
    for (int rt = 0; rt < 4; ++rt)
      a[rt] = *(const half8*)(A + (size_t)(rt*16 + l15)*lda + kc*32 + q*8);
    #pragma unroll
    for (int ct = 0; ct < 4; ++ct)
      b[ct] = *(const half8*)(Bt + (size_t)kc*nstr*32 + (ct*16 + l15)*32 + q*8);
    #pragma unroll
    for (int rt = 0; rt < 4; ++rt)
      #pragma unroll
      for (int ct = 0; ct < 4; ++ct)
        acc[rt][ct] = __builtin_amdgcn_mfma_f32_16x16x32_f16(a[rt], b[ct], acc[rt][ct], 0,0,0);
  }
}

// K-split reduce through LDS (48KB). Returns true for the epilogue wave (wid 0).
__device__ __forceinline__ bool ksplit_reduce(f32x4 (&acc)[4][4], float* red,
                                              int wid, int lane) {
  if (wid > 0) {
    float* dst = red + (wid - 1) * 4096;
    #pragma unroll
    for (int rt = 0; rt < 4; ++rt)
      #pragma unroll
      for (int ct = 0; ct < 4; ++ct)
        *(f32x4*)(dst + ((rt*4 + ct)*64 + lane)*4) = acc[rt][ct];
  }
  __syncthreads();
  if (wid > 0) return false;
  #pragma unroll
  for (int w = 0; w < 3; ++w)
    #pragma unroll
    for (int rt = 0; rt < 4; ++rt)
      #pragma unroll
      for (int ct = 0; ct < 4; ++ct)
        acc[rt][ct] += *(const f32x4*)(red + w*4096 + ((rt*4 + ct)*64 + lane)*4);
  return true;
}

// ---- prep: M (plain+T32), S_r (+ Qs lag-0 seed), G col0, wod, hidden->fp16 ----
__global__ __launch_bounds__(256) void prep_kernel(
    const float* __restrict__ Wh, const float* __restrict__ Wo,
    const float* __restrict__ hidden,
    u16* __restrict__ Mp0, u16* __restrict__ Mt0,
    u16* __restrict__ Sr, float* __restrict__ G,
    float* __restrict__ wod, u16* __restrict__ Hf, u16* __restrict__ Qs) {
  int idx = blockIdx.x * 256 + threadIdx.x;
  if (idx < 262144) {                       // M[k][n] = Wh[n][16+k]
    int k = idx >> 9, n = idx & 511;
    u16 v = f2h(Wh[n*529 + 16 + k]);
    Mp0[k*512 + n] = v;
    Mt0[(k>>5)*16384 + n*32 + (k&31)] = v;
    return;
  }
  idx -= 262144;
  if (idx < 8704) {                         // S_r[q][n]; Qs lag-0 seed
    int q = idx >> 9, n = idx & 511;
    u16 v = f2h(Wh[n*529 + (q < 16 ? q : 528)]);
    Sr[idx] = v;
    Qs[idx] = v;
    return;
  }
  idx -= 8704;
  if (idx < 512) { G[idx*128 + 0] = Wo[16 + idx]; return; }
  idx -= 512;
  if (idx < 17) { wod[idx] = Wo[idx < 16 ? idx : 528]; return; }
  idx -= 17;
  if (idx < 131072) Hf[idx] = f2h(hidden[idx]);
}

// ---- level l: sq M^(2^l); append Q lags [m,2m); append G cols [m,2m); A-build filler ----
__global__ __launch_bounds__(256) void level_kernel(
    const u16* __restrict__ Mp_in, const u16* __restrict__ Mt_in,
    u16* __restrict__ Mp_out, u16* __restrict__ Mt_out,
    u16* __restrict__ Qs, float* __restrict__ G,
    const float* __restrict__ x, const float* __restrict__ cost,
    u16* __restrict__ A, int l) {
  __shared__ float red[12288];
  const int m = 1 << l;
  const int nq8 = (l <= 6) ? (((17*m + 63) >> 6) * 8) : 0;
  const int tid = threadIdx.x, bx = blockIdx.x;
  const int wid = tid >> 6, lane = tid & 63, q = lane >> 4, l15 = lane & 15;

  if (bx < 64) {  // square: 64x64 tile, K-split-4 over 16 kc
    int row0 = (bx >> 3) * 64, c0 = (bx & 7) * 64;
    f32x4 acc[4][4];
    wave_gemm(Mp_in + (size_t)row0*512, 512, Mt_in + (size_t)c0*32, 512,
              wid*4, wid*4 + 4, lane, acc);
    if (!ksplit_reduce(acc, red, wid, lane)) return;
    #pragma unroll
    for (int rt = 0; rt < 4; ++rt)
      for (int ct = 0; ct < 4; ++ct)
        for (int r = 0; r < 4; ++r) {
          int row = row0 + rt*16 + q*4 + r, col = c0 + ct*16 + l15;
          u16 v = f2h(acc[rt][ct][r]);
          Mp_out[row*512 + col] = v;
          Mt_out[(row>>5)*16384 + col*32 + (row&31)] = v;
        }
    return;
  }
  if (l <= 6 && bx < 64 + nq8) {  // Q append: rows [0,17m) @ M^m -> [17m,34m)
    int bq = bx - 64;
    int row0 = (bq >> 3) * 64, c0 = (bq & 7) * 64;
    f32x4 acc[4][4];
    wave_gemm(Qs + (size_t)row0*512, 512, Mt_in + (size_t)c0*32, 512,
              wid*4, wid*4 + 4, lane, acc);
    if (!ksplit_reduce(acc, red, wid, lane)) return;
    int lim = 17*m;
    #pragma unroll
    for (int rt = 0; rt < 4; ++rt)
      for (int ct = 0; ct < 4; ++ct)
        for (int r = 0; r < 4; ++r) {
          int rowIn = row0 + rt*16 + q*4 + r, col = c0 + ct*16 + l15;
          if (rowIn < lim) Qs[(size_t)(lim + rowIn)*512 + col] = f2h(acc[rt][ct][r]);
        }
    return;
  }
  if (l <= 6 && bx < 64 + nq8 + 32) {  // G append: G[:, m+c] = M^m @ G[:, c]
    int n0 = (bx - 64 - nq8) * 16;
    for (int idx = tid; idx < 16*m; idx += 256) {
      int c = idx & (m - 1), n = n0 + (idx >> l);
      const u16* mrow = Mp_in + n*512;
      float s0 = 0.f, s1 = 0.f, s2 = 0.f, s3 = 0.f;
      for (int k = 0; k < 512; k += 4) {
        s0 += h2f(mrow[k])   * G[k*128 + c];
        s1 += h2f(mrow[k+1]) * G[(k+1)*128 + c];
        s2 += h2f(mrow[k+2]) * G[(k+2)*128 + c];
        s3 += h2f(mrow[k+3]) * G[(k+3)*128 + c];
      }
      G[n*128 + m + c] = (s0 + s1) + (s2 + s3);
    }
    return;
  }
  // A-build filler: 205 WGs/level (last level 203), 2 rows each
  int abx = bx - (64 + ((l <= 6) ? nq8 + 32 : 0));
  int r = (l*205 + abx)*2 + (tid >> 7);
  if (r >= 4096) return;
  int s = tid & 127;
  int i = r >> 8, b = r & 255, t = i*128 + s;
  const float* xp = x + ((size_t)b*2048 + t)*16;
  u16* ap = A + (size_t)r*KTOT + s*17;
  #pragma unroll
  for (int p = 0; p < 16; p += 4) {
    float4 v = *(const float4*)(xp + p);
    ap[p] = f2h(v.x); ap[p+1] = f2h(v.y); ap[p+2] = f2h(v.z); ap[p+3] = f2h(v.w);
  }
  ap[16] = f2h(cost[(size_t)b*2048 + t]);
}

// ---- Cb[q][lam] = sum_k Sr[q][k] * G[k][lam] ----
__global__ void cbar_kernel(const u16* __restrict__ Sr, const float* __restrict__ G,
                            float* __restrict__ Cb) {
  int qq = blockIdx.x, lam = threadIdx.x;
  float s0 = 0.f, s1 = 0.f, s2 = 0.f, s3 = 0.f;
  for (int k = 0; k < 512; k += 4) {
    s0 += h2f(Sr[qq*512 + k])   * G[k*128 + lam];
    s1 += h2f(Sr[qq*512 + k+1]) * G[(k+1)*128 + lam];
    s2 += h2f(Sr[qq*512 + k+2]) * G[(k+2)*128 + lam];
    s3 += h2f(Sr[qq*512 + k+3]) * G[(k+3)*128 + lam];
  }
  Cb[qq*128 + lam] = (s0 + s1) + (s2 + s3);
}

// ---- build B (T32, 640 cols) + Gt (T32 of G) ----
__global__ void bbuild_kernel(const u16* __restrict__ Qs, const float* __restrict__ Cb,
                              const float* __restrict__ wod, const float* __restrict__ G,
                              u16* __restrict__ Bt, u16* __restrict__ Gt) {
  int idx = blockIdx.x * 256 + threadIdx.x;
  if (idx < KTOT * NBIG) {
    int krow = idx / NBIG, n = idx - krow * NBIG;
    int kc = krow >> 5, kk = krow & 31;
    int s = krow / 17, qq = krow - s * 17;
    u16 v;
    if (n < 512) {
      v = Qs[(size_t)((127 - s)*17 + qq)*512 + n];
    } else {
      int j = n - 512;
      if (s < j)       v = f2h(Cb[qq*128 + (j - 1 - s)]);
      else if (s == j) v = f2h(wod[qq]);
      else             v = 0;
    }
    Bt[(size_t)kc*(NBIG*32) + n*32 + kk] = v;
    return;
  }
  idx -= KTOT * NBIG;
  if (idx < 512*128) {
    int k = idx >> 7, j = idx & 127;
    Gt[(k>>5)*4096 + j*32 + (k&31)] = f2h(G[k*128 + j]);
  }
}

// ---- big GEMM [4096 x 640 x 2176], K-split-4 (17 kc/wave) ----
__global__ __launch_bounds__(256) void biggemm_kernel(const u16* __restrict__ A,
                                                      const u16* __restrict__ Bt,
                                                      u16* __restrict__ V0,
                                                      float* __restrict__ out) {
  __shared__ float red[12288];
  int colg = blockIdx.x >> 6, rowg = blockIdx.x & 63;
  const int tid = threadIdx.x, wid = tid >> 6, lane = tid & 63;
  const int q = lane >> 4, l15 = lane & 15;
  int row0 = rowg*64, c0 = colg*64;
  f32x4 acc[4][4];
  wave_gemm(A + (size_t)row0*KTOT, KTOT, Bt + (size_t)c0*32, NBIG,
            wid*17, wid*17 + 17, lane, acc);
  if (!ksplit_reduce(acc, red, wid, lane)) return;
  #pragma unroll
  for (int rt = 0; rt < 4; ++rt)
    for (int ct = 0; ct < 4; ++ct)
      for (int r = 0; r < 4; ++r) {
        int rg = row0 + rt*16 + q*4 + r, col = c0 + ct*16 + l15;
        if (col < 512) {
          V0[(size_t)rg*512 + col] = f2h(acc[rt][ct][r]);
        } else {
          int j = col - 512, b = rg & 255, i = rg >> 8;
          out[(size_t)b*2048 + i*128 + j] = acc[rt][ct][r];
        }
      }
}

// ---- scan round: Vdst[i] = Vsrc[i-d]@M^(128d) + Vsrc[i]; i-d==-1 uses Hf ----
__global__ __launch_bounds__(256) void scan_kernel(const u16* __restrict__ Vsrc,
                                                   u16* __restrict__ Vdst,
                                                   const u16* __restrict__ Mt,
                                                   const u16* __restrict__ Hf, int d) {
  __shared__ float red[12288];
  int bx = blockIdx.x;
  int i = bx >> 5, rowg = (bx >> 3) & 3, colg = bx & 7;
  const int tid = threadIdx.x, wid = tid >> 6, lane = tid & 63;
  const int q = lane >> 4, l15 = lane & 15;
  int row0 = rowg*64, c0 = colg*64;
  int src_i = i - d;
  if (src_i >= -1) {
    const u16* Asrc = (src_i >= 0) ? Vsrc + (size_t)(src_i*256 + row0)*512
                                   : Hf + (size_t)row0*512;
    f32x4 acc[4][4];
    wave_gemm(Asrc, 512, Mt + (size_t)c0*32, 512, wid*4, wid*4 + 4, lane, acc);
    if (!ksplit_reduce(acc, red, wid, lane)) return;
    #pragma unroll
    for (int rt = 0; rt < 4; ++rt)
      for (int ct = 0; ct < 4; ++ct)
        for (int r = 0; r < 4; ++r) {
          int rg = i*256 + row0 + rt*16 + q*4 + r, col = c0 + ct*16 + l15;
          Vdst[(size_t)rg*512 + col] = f2h(acc[rt][ct][r] + h2f(Vsrc[(size_t)rg*512 + col]));
        }
  } else {
    for (int it = tid; it < 512; it += 256) {
      int rl = it >> 3, cu = it & 7;
      size_t o = (size_t)(i*256 + row0 + rl)*512 + colg*64 + cu*8;
      *(uint4*)(Vdst + o) = *(const uint4*)(Vsrc + o);
    }
  }
}

// ---- final: out[b][i*128+j] += Pprev[(i,b)].g_j ; plus h_final = P_15 copy ----
__global__ __launch_bounds__(256) void final_kernel(const u16* __restrict__ V0,
                                                    const u16* __restrict__ Hf,
                                                    const u16* __restrict__ Gt,
                                                    float* __restrict__ out) {
  __shared__ float red[12288];
  const int bx = blockIdx.x, tid = threadIdx.x;
  if (bx >= 128) {  // h_final = P_15
    int idx = (bx - 128)*256 + tid;
    int base = idx * 8;
    int row = 3840 + (base >> 9), col = base & 511;
    const u16* vp = V0 + (size_t)row*512 + col;
    float* hp = out + 524288 + base;
    #pragma unroll
    for (int e = 0; e < 8; ++e) hp[e] = h2f(vp[e]);
    return;
  }
  int rowg = bx >> 1, colg = bx & 1;
  const int wid = tid >> 6, lane = tid & 63;
  const int q = lane >> 4, l15 = lane & 15;
  int row0 = rowg*64, c0 = colg*64;
  const u16* Abase = (row0 < 256) ? (Hf + (size_t)row0*512) : (V0 + (size_t)(row0-256)*512);
  f32x4 acc[4][4];
  wave_gemm(Abase, 512, Gt + (size_t)c0*32, 128, wid*4, wid*4 + 4, lane, acc);
  if (!ksplit_reduce(acc, red, wid, lane)) return;
  #pragma unroll
  for (int rt = 0; rt < 4; ++rt)
    for (int ct = 0; ct < 4; ++ct)
      for (int r = 0; r < 4; ++r) {
        int rg = row0 + rt*16 + q*4 + r, j = c0 + ct*16 + l15;
        int b = rg & 255, i = rg >> 8;
        out[(size_t)b*2048 + i*128 + j] += acc[rt][ct][r];
      }
}

extern "C" void kernel_launch(void* const* d_in, const int* in_sizes, int n_in,
                              void* d_out, int out_size, void* d_ws, size_t ws_size,
                              hipStream_t stream) {
  (void)in_sizes; (void)n_in; (void)out_size; (void)ws_size;
  const float* x      = (const float*)d_in[0];
  const float* hidden = (const float*)d_in[1];
  const float* cost   = (const float*)d_in[2];
  const float* Wo     = (const float*)d_in[3];
  const float* Wh     = (const float*)d_in[4];
  float* out = (float*)d_out;
  char* ws = (char*)d_ws;

  auto Mp = [&](int l){ return (u16*)(ws + (size_t)l*524288); };
  auto Mt = [&](int l){ return (u16*)(ws + 5767168 + (size_t)l*524288); };
  u16*   Qs  = (u16*)(ws + 11534336);   // 2176 x 512
  float* G   = (float*)(ws + 13762560); // 512 x 128
  u16*   Sr  = (u16*)(ws + 14024704);   // 17 x 512
  float* wod = (float*)(ws + 14057472); // 17
  float* Cb  = (float*)(ws + 14057728); // 17 x 128
  u16*   Hf  = (u16*)(ws + 14074112);   // 256 x 512
  u16*   Bt  = (u16*)(ws + 14336256);   // T32 2176 x 640
  u16*   Gt  = (u16*)(ws + 17121536);   // T32 512 x 128
  u16*   A   = (u16*)(ws + 17252608);   // 4096 x 2176
  u16*   V0  = (u16*)(ws + 35078400);   // 4096 x 512
  u16*   V1  = (u16*)(ws + 39272704);   // 4096 x 512

  prep_kernel<<<1573, 256, 0, stream>>>(Wh, Wo, hidden, Mp(0), Mt(0), Sr, G, wod, Hf, Qs);
  for (int l = 0; l <= 9; ++l) {
    int m = 1 << l;
    int nq8 = (l <= 6) ? (((17*m + 63) >> 6) * 8) : 0;
    int abn = (l == 9) ? 203 : 205;
    int grid = 64 + ((l <= 6) ? nq8 + 32 : 0) + abn;
    level_kernel<<<grid, 256, 0, stream>>>(Mp(l), Mt(l), Mp(l+1), Mt(l+1),
                                           Qs, G, x, cost, A, l);
  }
  cbar_kernel<<<17, 128, 0, stream>>>(Sr, G, Cb);
  bbuild_kernel<<<(KTOT*NBIG + 512*128 + 255)/256, 256, 0, stream>>>(Qs, Cb, wod, G, Bt, Gt);
  biggemm_kernel<<<640, 256, 0, stream>>>(A, Bt, V0, out);
  scan_kernel<<<512, 256, 0, stream>>>(V0, V1, Mt(7), Hf, 1);
  scan_kernel<<<512, 256, 0, stream>>>(V1, V0, Mt(8), Hf, 2);
  scan_kernel<<<512, 256, 0, stream>>>(V0, V1, Mt(9), Hf, 4);
  scan_kernel<<<512, 256, 0, stream>>>(V1, V0, Mt(10), Hf, 8);
  final_kernel<<<192, 256, 0, stream>>>(V0, Hf, Gt, out);
}

// Round 7
// 309.108 us; speedup vs baseline: 4.7462x; 1.0489x over previous
//
#include <hip/hip_runtime.h>

// Linear-RNN via pure GEMM decomposition (no per-step loop).
//   h_{t+1} = h_t@M + x̄_t@S ;  o_t = x̄_t·wod + h_t·woh
//   v_i = A_i @ W̃ ; o = A_i @ T + P_{i-1}@G ; P = scan(v, M^128 powers)
// R7: software-pipelined wave_gemm (register prefetch of next kc);
// M^256/M^512/M^1024 squarings folded into biggemm/scan1/scan2 as filler WGs
// (level chain now l=0..6 only); A-build filler redistributed over 7 levels.
// NOTE: wave_gemm prefetches one 32-panel past each operand; all such reads
// stay inside the workspace (verified against the layout below).

typedef __attribute__((ext_vector_type(8))) _Float16 half8;
typedef __attribute__((ext_vector_type(4))) float f32x4;
typedef unsigned short u16;

#define KTOT 2176   // 128*17
#define NBIG 640    // 512 V cols + 128 conv cols

__device__ __forceinline__ u16 f2h(float f) {
  union { _Float16 h; u16 u; } v; v.h = (_Float16)f; return v.u;
}
__device__ __forceinline__ float h2f(u16 u) {
  union { u16 u; _Float16 h; } v; v.u = u; return (float)v.h;
}

// wave: 64x64 tile over kc in [kc0,kcN), software-pipelined (prefetch kc+1).
// A plain fp16 pre-offset to row0 (lda elems); Bt T32 pre-offset to col base.
__device__ __forceinline__ void wave_gemm(const u16* __restrict__ A, int lda,
                                          const u16* __restrict__ Bt, int nstr,
                                          int kc0, int kcN, int lane,
                                          f32x4 (&acc)[4][4]) {
  const int q = lane >> 4, l15 = lane & 15;
  #pragma unroll
  for (int rt = 0; rt < 4; ++rt)
    #pragma unroll
    for (int ct = 0; ct < 4; ++ct) { f32x4 z = {0.f,0.f,0.f,0.f}; acc[rt][ct] = z; }
  const u16* aP = A + (size_t)l15*lda + (size_t)kc0*32 + q*8;
  const u16* bP = Bt + ((size_t)kc0*nstr + l15)*32 + q*8;
  half8 a[4], b[4];
  #pragma unroll
  for (int rt = 0; rt < 4; ++rt) a[rt] = *(const half8*)(aP + (size_t)(rt*16)*lda);
  #pragma unroll
  for (int ct = 0; ct < 4; ++ct) b[ct] = *(const half8*)(bP + ct*512);
  for (int kc = kc0; kc < kcN; ++kc) {
    const u16* aN = aP + 32;
    const u16* bN = bP + (size_t)nstr*32;
    half8 an[4], bn[4];
    #pragma unroll
    for (int rt = 0; rt < 4; ++rt) an[rt] = *(const half8*)(aN + (size_t)(rt*16)*lda);
    #pragma unroll
    for (int ct = 0; ct < 4; ++ct) bn[ct] = *(const half8*)(bN + ct*512);
    #pragma unroll
    for (int rt = 0; rt < 4; ++rt)
      #pragma unroll
      for (int ct = 0; ct < 4; ++ct)
        acc[rt][ct] = __builtin_amdgcn_mfma_f32_16x16x32_f16(a[rt], b[ct], acc[rt][ct], 0,0,0);
    #pragma unroll
    for (int rt = 0; rt < 4; ++rt) a[rt] = an[rt];
    #pragma unroll
    for (int ct = 0; ct < 4; ++ct) b[ct] = bn[ct];
    aP = aN; bP = bN;
  }
}

// K-split reduce through LDS (48KB). Returns true for the epilogue wave (wid 0).
__device__ __forceinline__ bool ksplit_reduce(f32x4 (&acc)[4][4], float* red,
                                              int wid, int lane) {
  if (wid > 0) {
    float* dst = red + (wid - 1) * 4096;
    #pragma unroll
    for (int rt = 0; rt < 4; ++rt)
      #pragma unroll
      for (int ct = 0; ct < 4; ++ct)
        *(f32x4*)(dst + ((rt*4 + ct)*64 + lane)*4) = acc[rt][ct];
  }
  __syncthreads();
  if (wid > 0) return false;
  #pragma unroll
  for (int w = 0; w < 3; ++w)
    #pragma unroll
    for (int rt = 0; rt < 4; ++rt)
      #pragma unroll
      for (int ct = 0; ct < 4; ++ct)
        acc[rt][ct] += *(const f32x4*)(red + w*4096 + ((rt*4 + ct)*64 + lane)*4);
  return true;
}

// one 64x64 tile of a 512x512 squaring: (Mp_in @ Mt_in) -> Mp_out, Mt_out
__device__ __forceinline__ void square_tile(const u16* __restrict__ Mp_in,
                                            const u16* __restrict__ Mt_in,
                                            u16* __restrict__ Mp_out,
                                            u16* __restrict__ Mt_out,
                                            int bx, float* red, int tid) {
  const int wid = tid >> 6, lane = tid & 63, q = lane >> 4, l15 = lane & 15;
  int row0 = (bx >> 3) * 64, c0 = (bx & 7) * 64;
  f32x4 acc[4][4];
  wave_gemm(Mp_in + (size_t)row0*512, 512, Mt_in + (size_t)c0*32, 512,
            wid*4, wid*4 + 4, lane, acc);
  if (!ksplit_reduce(acc, red, wid, lane)) return;
  #pragma unroll
  for (int rt = 0; rt < 4; ++rt)
    for (int ct = 0; ct < 4; ++ct)
      for (int r = 0; r < 4; ++r) {
        int row = row0 + rt*16 + q*4 + r, col = c0 + ct*16 + l15;
        u16 v = f2h(acc[rt][ct][r]);
        Mp_out[row*512 + col] = v;
        Mt_out[(row>>5)*16384 + col*32 + (row&31)] = v;
      }
}

// ---- prep: M (plain+T32), S_r (+ Qs lag-0 seed), G col0, wod, hidden->fp16 ----
__global__ __launch_bounds__(256) void prep_kernel(
    const float* __restrict__ Wh, const float* __restrict__ Wo,
    const float* __restrict__ hidden,
    u16* __restrict__ Mp0, u16* __restrict__ Mt0,
    u16* __restrict__ Sr, float* __restrict__ G,
    float* __restrict__ wod, u16* __restrict__ Hf, u16* __restrict__ Qs) {
  int idx = blockIdx.x * 256 + threadIdx.x;
  if (idx < 262144) {                       // M[k][n] = Wh[n][16+k]
    int k = idx >> 9, n = idx & 511;
    u16 v = f2h(Wh[n*529 + 16 + k]);
    Mp0[k*512 + n] = v;
    Mt0[(k>>5)*16384 + n*32 + (k&31)] = v;
    return;
  }
  idx -= 262144;
  if (idx < 8704) {                         // S_r[q][n]; Qs lag-0 seed
    int q = idx >> 9, n = idx & 511;
    u16 v = f2h(Wh[n*529 + (q < 16 ? q : 528)]);
    Sr[idx] = v;
    Qs[idx] = v;
    return;
  }
  idx -= 8704;
  if (idx < 512) { G[idx*128 + 0] = Wo[16 + idx]; return; }
  idx -= 512;
  if (idx < 17) { wod[idx] = Wo[idx < 16 ? idx : 528]; return; }
  idx -= 17;
  if (idx < 131072) Hf[idx] = f2h(hidden[idx]);
}

// ---- level l (0..6): sq M^(2^l); Q lags [m,2m); G cols [m,2m); A-build filler ----
__global__ __launch_bounds__(256) void level_kernel(
    const u16* __restrict__ Mp_in, const u16* __restrict__ Mt_in,
    u16* __restrict__ Mp_out, u16* __restrict__ Mt_out,
    u16* __restrict__ Qs, float* __restrict__ G,
    const float* __restrict__ x, const float* __restrict__ cost,
    u16* __restrict__ A, int l) {
  __shared__ float red[12288];
  const int m = 1 << l;
  const int nq8 = (((17*m + 63) >> 6)) * 8;
  const int tid = threadIdx.x, bx = blockIdx.x;
  const int wid = tid >> 6, lane = tid & 63, q = lane >> 4, l15 = lane & 15;

  if (bx < 64) {  // square
    square_tile(Mp_in, Mt_in, Mp_out, Mt_out, bx, red, tid);
    return;
  }
  if (bx < 64 + nq8) {  // Q append: rows [0,17m) @ M^m -> [17m,34m)
    int bq = bx - 64;
    int row0 = (bq >> 3) * 64, c0 = (bq & 7) * 64;
    f32x4 acc[4][4];
    wave_gemm(Qs + (size_t)row0*512, 512, Mt_in + (size_t)c0*32, 512,
              wid*4, wid*4 + 4, lane, acc);
    if (!ksplit_reduce(acc, red, wid, lane)) return;
    int lim = 17*m;
    #pragma unroll
    for (int rt = 0; rt < 4; ++rt)
      for (int ct = 0; ct < 4; ++ct)
        for (int r = 0; r < 4; ++r) {
          int rowIn = row0 + rt*16 + q*4 + r, col = c0 + ct*16 + l15;
          if (rowIn < lim) Qs[(size_t)(lim + rowIn)*512 + col] = f2h(acc[rt][ct][r]);
        }
    return;
  }
  if (bx < 64 + nq8 + 32) {  // G append: G[:, m+c] = M^m @ G[:, c]
    int n0 = (bx - 64 - nq8) * 16;
    for (int idx = tid; idx < 16*m; idx += 256) {
      int c = idx & (m - 1), n = n0 + (idx >> l);
      const u16* mrow = Mp_in + n*512;
      float s0 = 0.f, s1 = 0.f, s2 = 0.f, s3 = 0.f;
      for (int k = 0; k < 512; k += 4) {
        s0 += h2f(mrow[k])   * G[k*128 + c];
        s1 += h2f(mrow[k+1]) * G[(k+1)*128 + c];
        s2 += h2f(mrow[k+2]) * G[(k+2)*128 + c];
        s3 += h2f(mrow[k+3]) * G[(k+3)*128 + c];
      }
      G[n*128 + m + c] = (s0 + s1) + (s2 + s3);
    }
    return;
  }
  // A-build filler: 293 WGs/level (l=6: 290), 2 rows each
  int abx = bx - (64 + nq8 + 32);
  int r = (l*293 + abx)*2 + (tid >> 7);
  if (r >= 4096) return;
  int s = tid & 127;
  int i = r >> 8, b = r & 255, t = i*128 + s;
  const float* xp = x + ((size_t)b*2048 + t)*16;
  u16* ap = A + (size_t)r*KTOT + s*17;
  #pragma unroll
  for (int p = 0; p < 16; p += 4) {
    float4 v = *(const float4*)(xp + p);
    ap[p] = f2h(v.x); ap[p+1] = f2h(v.y); ap[p+2] = f2h(v.z); ap[p+3] = f2h(v.w);
  }
  ap[16] = f2h(cost[(size_t)b*2048 + t]);
}

// ---- Cb[q][lam] = sum_k Sr[q][k] * G[k][lam] ----
__global__ void cbar_kernel(const u16* __restrict__ Sr, const float* __restrict__ G,
                            float* __restrict__ Cb) {
  int qq = blockIdx.x, lam = threadIdx.x;
  float s0 = 0.f, s1 = 0.f, s2 = 0.f, s3 = 0.f;
  for (int k = 0; k < 512; k += 4) {
    s0 += h2f(Sr[qq*512 + k])   * G[k*128 + lam];
    s1 += h2f(Sr[qq*512 + k+1]) * G[(k+1)*128 + lam];
    s2 += h2f(Sr[qq*512 + k+2]) * G[(k+2)*128 + lam];
    s3 += h2f(Sr[qq*512 + k+3]) * G[(k+3)*128 + lam];
  }
  Cb[qq*128 + lam] = (s0 + s1) + (s2 + s3);
}

// ---- build B (T32, 640 cols) + Gt (T32 of G) ----
__global__ void bbuild_kernel(const u16* __restrict__ Qs, const float* __restrict__ Cb,
                              const float* __restrict__ wod, const float* __restrict__ G,
                              u16* __restrict__ Bt, u16* __restrict__ Gt) {
  int idx = blockIdx.x * 256 + threadIdx.x;
  if (idx < KTOT * NBIG) {
    int krow = idx / NBIG, n = idx - krow * NBIG;
    int kc = krow >> 5, kk = krow & 31;
    int s = krow / 17, qq = krow - s * 17;
    u16 v;
    if (n < 512) {
      v = Qs[(size_t)((127 - s)*17 + qq)*512 + n];
    } else {
      int j = n - 512;
      if (s < j)       v = f2h(Cb[qq*128 + (j - 1 - s)]);
      else if (s == j) v = f2h(wod[qq]);
      else             v = 0;
    }
    Bt[(size_t)kc*(NBIG*32) + n*32 + kk] = v;
    return;
  }
  idx -= KTOT * NBIG;
  if (idx < 512*128) {
    int k = idx >> 7, j = idx & 127;
    Gt[(k>>5)*4096 + j*32 + (k&31)] = f2h(G[k*128 + j]);
  }
}

// ---- big GEMM [4096x640x2176], K-split-4; +64 WGs square M^128->M^256 ----
__global__ __launch_bounds__(256) void biggemm_kernel(const u16* __restrict__ A,
                                                      const u16* __restrict__ Bt,
                                                      u16* __restrict__ V0,
                                                      float* __restrict__ out,
                                                      const u16* __restrict__ Mp7,
                                                      const u16* __restrict__ Mt7,
                                                      u16* __restrict__ Mp8,
                                                      u16* __restrict__ Mt8) {
  __shared__ float red[12288];
  const int bx = blockIdx.x, tid = threadIdx.x;
  if (bx >= 640) { square_tile(Mp7, Mt7, Mp8, Mt8, bx - 640, red, tid); return; }
  int colg = bx >> 6, rowg = bx & 63;
  const int wid = tid >> 6, lane = tid & 63;
  const int q = lane >> 4, l15 = lane & 15;
  int row0 = rowg*64, c0 = colg*64;
  f32x4 acc[4][4];
  wave_gemm(A + (size_t)row0*KTOT, KTOT, Bt + (size_t)c0*32, NBIG,
            wid*17, wid*17 + 17, lane, acc);
  if (!ksplit_reduce(acc, red, wid, lane)) return;
  #pragma unroll
  for (int rt = 0; rt < 4; ++rt)
    for (int ct = 0; ct < 4; ++ct)
      for (int r = 0; r < 4; ++r) {
        int rg = row0 + rt*16 + q*4 + r, col = c0 + ct*16 + l15;
        if (col < 512) {
          V0[(size_t)rg*512 + col] = f2h(acc[rt][ct][r]);
        } else {
          int j = col - 512, b = rg & 255, i = rg >> 8;
          out[(size_t)b*2048 + i*128 + j] = acc[rt][ct][r];
        }
      }
}

// ---- scan round: Vdst[i] = Vsrc[i-d]@M^(128d) + Vsrc[i]; i-d==-1 uses Hf.
//      bx>=512 (rounds 1,2 only): square next M-power for a later round. ----
__global__ __launch_bounds__(256) void scan_kernel(const u16* __restrict__ Vsrc,
                                                   u16* __restrict__ Vdst,
                                                   const u16* __restrict__ Mt,
                                                   const u16* __restrict__ Hf, int d,
                                                   const u16* __restrict__ Mp_si,
                                                   const u16* __restrict__ Mt_si,
                                                   u16* __restrict__ Mp_so,
                                                   u16* __restrict__ Mt_so) {
  __shared__ float red[12288];
  const int bx = blockIdx.x, tid = threadIdx.x;
  if (bx >= 512) { square_tile(Mp_si, Mt_si, Mp_so, Mt_so, bx - 512, red, tid); return; }
  int i = bx >> 5, rowg = (bx >> 3) & 3, colg = bx & 7;
  const int wid = tid >> 6, lane = tid & 63;
  const int q = lane >> 4, l15 = lane & 15;
  int row0 = rowg*64, c0 = colg*64;
  int src_i = i - d;
  if (src_i >= -1) {
    const u16* Asrc = (src_i >= 0) ? Vsrc + (size_t)(src_i*256 + row0)*512
                                   : Hf + (size_t)row0*512;
    f32x4 acc[4][4];
    wave_gemm(Asrc, 512, Mt + (size_t)c0*32, 512, wid*4, wid*4 + 4, lane, acc);
    if (!ksplit_reduce(acc, red, wid, lane)) return;
    #pragma unroll
    for (int rt = 0; rt < 4; ++rt)
      for (int ct = 0; ct < 4; ++ct)
        for (int r = 0; r < 4; ++r) {
          int rg = i*256 + row0 + rt*16 + q*4 + r, col = c0 + ct*16 + l15;
          Vdst[(size_t)rg*512 + col] = f2h(acc[rt][ct][r] + h2f(Vsrc[(size_t)rg*512 + col]));
        }
  } else {
    for (int it = tid; it < 512; it += 256) {
      int rl = it >> 3, cu = it & 7;
      size_t o = (size_t)(i*256 + row0 + rl)*512 + colg*64 + cu*8;
      *(uint4*)(Vdst + o) = *(const uint4*)(Vsrc + o);
    }
  }
}

// ---- final: out[b][i*128+j] += Pprev[(i,b)].g_j ; plus h_final = P_15 copy ----
__global__ __launch_bounds__(256) void final_kernel(const u16* __restrict__ V0,
                                                    const u16* __restrict__ Hf,
                                                    const u16* __restrict__ Gt,
                                                    float* __restrict__ out) {
  __shared__ float red[12288];
  const int bx = blockIdx.x, tid = threadIdx.x;
  if (bx >= 128) {  // h_final = P_15
    int idx = (bx - 128)*256 + tid;
    int base = idx * 8;
    int row = 3840 + (base >> 9), col = base & 511;
    const u16* vp = V0 + (size_t)row*512 + col;
    float* hp = out + 524288 + base;
    #pragma unroll
    for (int e = 0; e < 8; ++e) hp[e] = h2f(vp[e]);
    return;
  }
  int rowg = bx >> 1, colg = bx & 1;
  const int wid = tid >> 6, lane = tid & 63;
  const int q = lane >> 4, l15 = lane & 15;
  int row0 = rowg*64, c0 = colg*64;
  const u16* Abase = (row0 < 256) ? (Hf + (size_t)row0*512) : (V0 + (size_t)(row0-256)*512);
  f32x4 acc[4][4];
  wave_gemm(Abase, 512, Gt + (size_t)c0*32, 128, wid*4, wid*4 + 4, lane, acc);
  if (!ksplit_reduce(acc, red, wid, lane)) return;
  #pragma unroll
  for (int rt = 0; rt < 4; ++rt)
    for (int ct = 0; ct < 4; ++ct)
      for (int r = 0; r < 4; ++r) {
        int rg = row0 + rt*16 + q*4 + r, j = c0 + ct*16 + l15;
        int b = rg & 255, i = rg >> 8;
        out[(size_t)b*2048 + i*128 + j] += acc[rt][ct][r];
      }
}

extern "C" void kernel_launch(void* const* d_in, const int* in_sizes, int n_in,
                              void* d_out, int out_size, void* d_ws, size_t ws_size,
                              hipStream_t stream) {
  (void)in_sizes; (void)n_in; (void)out_size; (void)ws_size;
  const float* x      = (const float*)d_in[0];
  const float* hidden = (const float*)d_in[1];
  const float* cost   = (const float*)d_in[2];
  const float* Wo     = (const float*)d_in[3];
  const float* Wh     = (const float*)d_in[4];
  float* out = (float*)d_out;
  char* ws = (char*)d_ws;

  auto Mp = [&](int l){ return (u16*)(ws + (size_t)l*524288); };
  auto Mt = [&](int l){ return (u16*)(ws + 5767168 + (size_t)l*524288); };
  u16*   Qs  = (u16*)(ws + 11534336);   // 2176 x 512
  float* G   = (float*)(ws + 13762560); // 512 x 128
  u16*   Sr  = (u16*)(ws + 14024704);   // 17 x 512
  float* wod = (float*)(ws + 14057472); // 17
  float* Cb  = (float*)(ws + 14057728); // 17 x 128
  u16*   Hf  = (u16*)(ws + 14074112);   // 256 x 512
  u16*   Bt  = (u16*)(ws + 14336256);   // T32 2176 x 640
  u16*   Gt  = (u16*)(ws + 17121536);   // T32 512 x 128
  u16*   A   = (u16*)(ws + 17252608);   // 4096 x 2176
  u16*   V0  = (u16*)(ws + 35078400);   // 4096 x 512
  u16*   V1  = (u16*)(ws + 39272704);   // 4096 x 512

  prep_kernel<<<1573, 256, 0, stream>>>(Wh, Wo, hidden, Mp(0), Mt(0), Sr, G, wod, Hf, Qs);
  for (int l = 0; l <= 6; ++l) {
    int m = 1 << l;
    int nq8 = ((17*m + 63) >> 6) * 8;
    int abn = (l == 6) ? 290 : 293;
    int grid = 64 + nq8 + 32 + abn;
    level_kernel<<<grid, 256, 0, stream>>>(Mp(l), Mt(l), Mp(l+1), Mt(l+1),
                                           Qs, G, x, cost, A, l);
  }
  cbar_kernel<<<17, 128, 0, stream>>>(Sr, G, Cb);
  bbuild_kernel<<<(KTOT*NBIG + 512*128 + 255)/256, 256, 0, stream>>>(Qs, Cb, wod, G, Bt, Gt);
  // biggemm + square M^128->M^256
  biggemm_kernel<<<704, 256, 0, stream>>>(A, Bt, V0, out, Mp(7), Mt(7), Mp(8), Mt(8));
  // scan1 (d=1, M^128) + square M^256->M^512
  scan_kernel<<<576, 256, 0, stream>>>(V0, V1, Mt(7), Hf, 1, Mp(8), Mt(8), Mp(9), Mt(9));
  // scan2 (d=2, M^256) + square M^512->M^1024
  scan_kernel<<<576, 256, 0, stream>>>(V1, V0, Mt(8), Hf, 2, Mp(9), Mt(9), Mp(10), Mt(10));
  scan_kernel<<<512, 256, 0, stream>>>(V0, V1, Mt(9), Hf, 4, Mp(10), Mt(10), Mp(10), Mt(10));
  scan_kernel<<<512, 256, 0, stream>>>(V1, V0, Mt(10), Hf, 8, Mp(10), Mt(10), Mp(10), Mt(10));
  final_kernel<<<192, 256, 0, stream>>>(V0, Hf, Gt, out);
}